// Round 8
// baseline (61.814 us; speedup 1.0000x reference)
//
#include <hip/hip_runtime.h>

#define NB 16     // batches
#define NV 19     // vertices
#define NE 361    // edges per graph
#define NL 256    // seq len
#define ND 64     // d_model
#define NTP 24    // padded tile count (exactly 6 per wave, no guards)
#define NEP (NTP * 16)  // 384 padded edges
#define ASTRIDE 136     // bf16 shorts per A row (272 B, 16B-aligned)
#define NPAIR 2         // (b,l) pairs per block

typedef __attribute__((ext_vector_type(8))) short bf16x8;
typedef __attribute__((ext_vector_type(4))) float f32x4;
typedef __attribute__((ext_vector_type(2))) __bf16 bf16v2;

union bf8u { unsigned u[4]; bf16x8 v; uint4 q; };

__device__ __forceinline__ unsigned pack_bf16(float lo, float hi) {
    bf16v2 v; v.x = (__bf16)lo; v.y = (__bf16)hi;   // -> v_cvt_pk_bf16_f32
    return __builtin_bit_cast(unsigned, v);
}
__device__ __forceinline__ short f2bf(float f) {
    __bf16 h = (__bf16)f;
    return __builtin_bit_cast(short, h);
}
__device__ __forceinline__ float bflo(unsigned u) {
    return __builtin_bit_cast(float, u << 16);
}
__device__ __forceinline__ float bfhi(unsigned u) {
    return __builtin_bit_cast(float, u & 0xffff0000u);
}
// packed-f32-friendly 4-wide silu: x * rcp(1 + exp2(-x*log2e))
__device__ __forceinline__ f32x4 silu4(f32x4 x) {
    f32x4 t = x * -1.44269504f;
    f32x4 d;
    d.x = __builtin_amdgcn_exp2f(t.x);
    d.y = __builtin_amdgcn_exp2f(t.y);
    d.z = __builtin_amdgcn_exp2f(t.z);
    d.w = __builtin_amdgcn_exp2f(t.w);
    d += 1.f;
    f32x4 r;
    r.x = __builtin_amdgcn_rcpf(d.x);
    r.y = __builtin_amdgcn_rcpf(d.y);
    r.z = __builtin_amdgcn_rcpf(d.z);
    r.w = __builtin_amdgcn_rcpf(d.w);
    return x * r;
}
__device__ __forceinline__ float sigm(float x) {
    return __builtin_amdgcn_rcpf(1.f + __builtin_amdgcn_exp2f(x * -1.44269504f));
}

// One block per 2 consecutive (b,l). 256 threads = 4 waves.
// launch_bounds(256,4): 128-VGPR cap — (256,6) forced spills (round 5: WRITE 161MB).
__global__ __launch_bounds__(256, 4) void edge_learner_kernel(
    const float* __restrict__ hs,      // (B*V, L, D)
    const float* __restrict__ ew_in,   // (B*E, L)
    const float* __restrict__ W1,      // (129, 64)
    const float* __restrict__ b1,      // (64,)
    const float* __restrict__ W2,      // (64, 32)
    const float* __restrict__ b2,      // (32,)
    const float* __restrict__ W3,      // (32, 1)
    const float* __restrict__ b3,      // (1,)
    const float* __restrict__ skip_p,  // (1,)
    const int*   __restrict__ eidx,    // (2, B*E, L)
    float* __restrict__ out)           // (B*E, L)
{
    __shared__ __align__(16) short A_s[NPAIR][NV * ASTRIDE];  // node projs + 0.5*b1, bf16
    __shared__ __align__(16) int4  meta_s[NPAIR][NEP];        // {srco, tgto, ew_bits, 0}

    const int tid  = threadIdx.x;
    const int lane = tid & 63;
    const int wave = tid >> 6;
    const int lq   = lane >> 4;    // quarter (k-group)
    const int lm   = lane & 15;    // row/col within fragment
    // XCD-contiguous swizzle: 2048 blocks, 256/XCD -> each XCD owns 2 whole batches
    const int bid0 = blockIdx.x;
    const int bid  = (bid0 & 7) * 256 + (bid0 >> 3);
    const int plb  = bid * 2;      // (b,l) flat base; even, so both pairs same b
    const int b    = plb >> 8;
    const int l0   = plb & 255;    // pair handles l0, l0+1

    // ---------- stage BOTH pairs' edge metadata in one burst (deep MLP) ----------
    for (int i = tid; i < NPAIR * NEP; i += 256) {
        const int p = (i >= NEP) ? 1 : 0;
        const int e = i - p * NEP;
        int4 m;
        if (e < NE) {
            size_t row = (size_t)(b * NE + e) * NL + l0 + p;
            m.x = (eidx[row] % NV) * ASTRIDE;
            m.y = (eidx[(size_t)NB * NE * NL + row] % NV) * ASTRIDE + 64;
            m.z = __builtin_bit_cast(int, ew_in[row]);
            m.w = 0;
        } else {
            m.x = 0; m.y = 64; m.z = 0; m.w = 0;
        }
        meta_s[p][e] = m;
    }

    // ---------- per-lane constants (loaded once for both pairs) ----------
    f32x4 w1lv[2][2];              // layer-1 ew row, ch(ks,i) = ks*32 + lq*8 + i
    #pragma unroll
    for (int ks = 0; ks < 2; ++ks) {
        w1lv[ks][0] = *(const f32x4*)&W1[128 * 64 + ks * 32 + lq * 8];
        w1lv[ks][1] = *(const f32x4*)&W1[128 * 64 + ks * 32 + lq * 8 + 4];
    }
    bf8u w2f[2][2];                // MFMA A operand = W2^T rows j = nt*16+lm
    #pragma unroll
    for (int nt = 0; nt < 2; ++nt)
        #pragma unroll
        for (int ks = 0; ks < 2; ++ks) {
            const float* w2p = &W2[(ks * 32 + lq * 8) * 32 + nt * 16 + lm];
            #pragma unroll
            for (int p = 0; p < 4; ++p)
                w2f[nt][ks].u[p] = pack_bf16(w2p[(2 * p) * 32], w2p[(2 * p + 1) * 32]);
        }
    const f32x4 b2v0 = *(const f32x4*)&b2[lq * 4];
    const f32x4 b2v1 = *(const f32x4*)&b2[16 + lq * 4];
    const f32x4 w3v0 = *(const f32x4*)&W3[lq * 4];
    const f32x4 w3v1 = *(const f32x4*)&W3[16 + lq * 4];
    const float b3v  = b3[0];
    const float skip = skip_p[0];

    // ---------- phase 2: A[p][v][c] via MFMA; wave w owns cols [32w, 32w+32) ----------
    {
        const int half = wave >> 1;
        const int oc0  = (wave & 1) * 32;
        const float hb0 = 0.5f * b1[(wave * 32 + lm) & 63];
        const float hb1 = 0.5f * b1[(wave * 32 + 16 + lm) & 63];
        bf8u w1f[2][2];   // [nt][ks] — pair-independent, loaded ONCE
        #pragma unroll
        for (int nt = 0; nt < 2; ++nt)
            #pragma unroll
            for (int ks = 0; ks < 2; ++ks) {
                const float* wp = &W1[(half * 64 + ks * 32 + lq * 8) * 64
                                      + oc0 + nt * 16 + lm];
                #pragma unroll
                for (int p = 0; p < 4; ++p)
                    w1f[nt][ks].u[p] = pack_bf16(wp[(2 * p) * 64], wp[(2 * p + 1) * 64]);
            }

        #pragma unroll
        for (int p = 0; p < NPAIR; ++p) {
            f32x4 acc00 = {0,0,0,0}, acc01 = {0,0,0,0},
                  acc10 = {0,0,0,0}, acc11 = {0,0,0,0};
            #pragma unroll
            for (int Mt = 0; Mt < 2; ++Mt) {
                int v  = Mt * 16 + lm;
                int vc = v < NV ? v : NV - 1;            // clamp pad rows
                const float* hp = hs + ((size_t)(b * NV + vc) * NL + l0 + p) * ND;
                bf8u af[2];
                #pragma unroll
                for (int ks = 0; ks < 2; ++ks) {
                    float4 x0 = *(const float4*)&hp[ks * 32 + lq * 8];
                    float4 x1 = *(const float4*)&hp[ks * 32 + lq * 8 + 4];
                    af[ks].u[0] = pack_bf16(x0.x, x0.y);
                    af[ks].u[1] = pack_bf16(x0.z, x0.w);
                    af[ks].u[2] = pack_bf16(x1.x, x1.y);
                    af[ks].u[3] = pack_bf16(x1.z, x1.w);
                }
                if (Mt == 0) {
                    acc00 = __builtin_amdgcn_mfma_f32_16x16x32_bf16(af[0].v, w1f[0][0].v, acc00, 0, 0, 0);
                    acc00 = __builtin_amdgcn_mfma_f32_16x16x32_bf16(af[1].v, w1f[0][1].v, acc00, 0, 0, 0);
                    acc01 = __builtin_amdgcn_mfma_f32_16x16x32_bf16(af[0].v, w1f[1][0].v, acc01, 0, 0, 0);
                    acc01 = __builtin_amdgcn_mfma_f32_16x16x32_bf16(af[1].v, w1f[1][1].v, acc01, 0, 0, 0);
                } else {
                    acc10 = __builtin_amdgcn_mfma_f32_16x16x32_bf16(af[0].v, w1f[0][0].v, acc10, 0, 0, 0);
                    acc10 = __builtin_amdgcn_mfma_f32_16x16x32_bf16(af[1].v, w1f[0][1].v, acc10, 0, 0, 0);
                    acc11 = __builtin_amdgcn_mfma_f32_16x16x32_bf16(af[0].v, w1f[1][0].v, acc11, 0, 0, 0);
                    acc11 = __builtin_amdgcn_mfma_f32_16x16x32_bf16(af[1].v, w1f[1][1].v, acc11, 0, 0, 0);
                }
            }
            // write A (bf16, +0.5*b1): row v, col c = wave*32 + {lm, 16+lm}
            #pragma unroll
            for (int r = 0; r < 4; ++r) {
                int v0 = lq * 4 + r;
                A_s[p][v0 * ASTRIDE + wave * 32 + lm]      = f2bf(acc00[r] + hb0);
                A_s[p][v0 * ASTRIDE + wave * 32 + 16 + lm] = f2bf(acc01[r] + hb1);
                int v1 = 16 + lq * 4 + r;
                if (v1 < NV) {
                    A_s[p][v1 * ASTRIDE + wave * 32 + lm]      = f2bf(acc10[r] + hb0);
                    A_s[p][v1 * ASTRIDE + wave * 32 + 16 + lm] = f2bf(acc11[r] + hb1);
                }
            }
        }
    }
    __syncthreads();   // the block's only barrier

    // ---------- phase 3: 2 pairs x 6 tiles/wave ----------
    #pragma unroll
    for (int p = 0; p < NPAIR; ++p) {
        const short* Ap = A_s[p];
        const int4*  mp = meta_s[p];
        float* outp = out + l0 + p;

        #pragma unroll
        for (int i = 0; i < 6; ++i) {
            const int t = wave + 4 * i;
            const int4 m = mp[t * 16 + lm];
            const int  so = m.x;
            const int  to = m.y;
            const float ew = __builtin_bit_cast(float, m.z);

            // layer 1: bf16 gathers, vector-form unpack+add (SLP -> pk_add), silu
            bf8u a1[2];
            #pragma unroll
            for (int ks = 0; ks < 2; ++ks) {
                const uint4 as = *(const uint4*)&Ap[so + ks * 32 + lq * 8];
                const uint4 at = *(const uint4*)&Ap[to + ks * 32 + lq * 8];
                f32x4 sv0 = { bflo(as.x), bfhi(as.x), bflo(as.y), bfhi(as.y) };
                f32x4 tv0 = { bflo(at.x), bfhi(at.x), bflo(at.y), bfhi(at.y) };
                f32x4 sv1 = { bflo(as.z), bfhi(as.z), bflo(as.w), bfhi(as.w) };
                f32x4 tv1 = { bflo(at.z), bfhi(at.z), bflo(at.w), bfhi(at.w) };
                f32x4 x0 = sv0 + tv0 + ew * w1lv[ks][0];
                f32x4 x1 = sv1 + tv1 + ew * w1lv[ks][1];
                f32x4 y0 = silu4(x0);
                f32x4 y1 = silu4(x1);
                a1[ks].u[0] = pack_bf16(y0.x, y0.y);
                a1[ks].u[1] = pack_bf16(y0.z, y0.w);
                a1[ks].u[2] = pack_bf16(y1.x, y1.y);
                a1[ks].u[3] = pack_bf16(y1.z, y1.w);
            }

            // layer 2: W2^T @ h1^T -> C[row=j, col=edge]  (4 MFMAs)
            f32x4 c0 = {0,0,0,0}, c1 = {0,0,0,0};
            c0 = __builtin_amdgcn_mfma_f32_16x16x32_bf16(w2f[0][0].v, a1[0].v, c0, 0, 0, 0);
            c0 = __builtin_amdgcn_mfma_f32_16x16x32_bf16(w2f[0][1].v, a1[1].v, c0, 0, 0, 0);
            c1 = __builtin_amdgcn_mfma_f32_16x16x32_bf16(w2f[1][0].v, a1[0].v, c1, 0, 0, 0);
            c1 = __builtin_amdgcn_mfma_f32_16x16x32_bf16(w2f[1][1].v, a1[1].v, c1, 0, 0, 0);

            // epilogue: silu over this lane's 8 j-rows (col = edge lm),
            // local dot with W3, 2-shuffle reduce over lq groups
            f32x4 h0 = silu4(c0 + b2v0);
            f32x4 h1 = silu4(c1 + b2v1);
            f32x4 pv = h0 * w3v0 + h1 * w3v1;
            float pr = (pv.x + pv.y) + (pv.z + pv.w);
            pr += __shfl_xor(pr, 16);
            pr += __shfl_xor(pr, 32);

            if (lane < 16) {
                int er = t * 16 + lane;
                if (er < NE) {
                    float wgt = sigm(pr + b3v);
                    outp[(size_t)(b * NE + er) * NL] = skip * ew + (1.f - skip) * wgt;
                }
            }
        }
    }
}

extern "C" void kernel_launch(void* const* d_in, const int* in_sizes, int n_in,
                              void* d_out, int out_size, void* d_ws, size_t ws_size,
                              hipStream_t stream) {
    const float* hs   = (const float*)d_in[0];
    const float* ew   = (const float*)d_in[1];
    const float* W1   = (const float*)d_in[2];
    const float* b1   = (const float*)d_in[3];
    const float* W2   = (const float*)d_in[4];
    const float* b2   = (const float*)d_in[5];
    const float* W3   = (const float*)d_in[6];
    const float* b3   = (const float*)d_in[7];
    const float* skip = (const float*)d_in[8];
    const int*   eidx = (const int*)d_in[9];
    float* outp = (float*)d_out;

    dim3 grid(NB * NL / NPAIR);   // 2048 blocks, one per 2 consecutive (b, l)
    dim3 block(256);
    hipLaunchKernelGGL(edge_learner_kernel, grid, block, 0, stream,
                       hs, ew, W1, b1, W2, b2, W3, b3, skip, eidx, outp);
}